// Round 1
// baseline (65.268 us; speedup 1.0000x reference)
//
#include <hip/hip_runtime.h>

#define X_H 4096
#define X_W 128
#define BATCH 4
#define CH 128
#define TT_OUT 2048
#define FF 64
#define EPS_GN 1e-3f

// workspace float offsets
#define WSUM_OFF 0
#define M_OFF 16
#define S1_OFF 128
#define SS_OFF (S1_OFF + BATCH*TT_OUT)
#define MU_OFF (SS_OFF + BATCH*TT_OUT)
#define ISTD_OFF (MU_OFF + BATCH*TT_OUT)

// ---------------- kernel 0: weight reductions ----------------
__global__ void prep_kernel(const float* __restrict__ w, float* __restrict__ ws) {
    int tid = threadIdx.x;
    if (tid < 81) {
        int j = tid / 9, k = tid % 9;
        float acc = 0.f;
        for (int c = 0; c < CH; ++c) acc = fmaf(w[c*9 + j], w[c*9 + k], acc);
        ws[M_OFF + tid] = acc;
    } else if (tid < 90) {
        int k = tid - 81;
        float acc = 0.f;
        for (int c = 0; c < CH; ++c) acc += w[c*9 + k];
        ws[WSUM_OFF + k] = acc;
    }
}

// ---------------- kernel 1: per-(b,t) S1, SS ----------------
// one wave per (b,t); lane = f
__global__ __launch_bounds__(256) void stats_kernel(const float* __restrict__ x,
                                                    float* __restrict__ ws) {
    int tid = threadIdx.x;
    int wid = blockIdx.x * 4 + (tid >> 6);      // b*2048 + t
    int lane = tid & 63;
    int t = wid & (TT_OUT - 1);
    int b = wid >> 11;
    int f = lane;
    const float* xb = x + (size_t)b * (X_H * X_W);
    float xv[9];
    int r0 = 2*t - 1;
#pragma unroll
    for (int kh = 0; kh < 3; ++kh) {
        int r = r0 + kh;
        bool rok = (r >= 0) && (r < X_H);
#pragma unroll
        for (int kw = 0; kw < 3; ++kw) {
            int cidx = 2*f + kw;
            xv[kh*3+kw] = (rok && cidx < X_W) ? xb[(size_t)r * X_W + cidx] : 0.f;
        }
    }
    float s1 = 0.f, ss = 0.f;
#pragma unroll
    for (int k = 0; k < 9; ++k) s1 = fmaf(ws[WSUM_OFF + k], xv[k], s1);
#pragma unroll
    for (int j = 0; j < 9; ++j) {
        float tj = 0.f;
#pragma unroll
        for (int k = 0; k < 9; ++k) tj = fmaf(ws[M_OFF + j*9 + k], xv[k], tj);
        ss = fmaf(xv[j], tj, ss);
    }
#pragma unroll
    for (int off = 32; off > 0; off >>= 1) {
        s1 += __shfl_xor(s1, off);
        ss += __shfl_xor(ss, off);
    }
    if (lane == 0) {
        ws[S1_OFF + wid] = s1;
        ws[SS_OFF + wid] = ss;
    }
}

// ---------------- kernel 2: cumulative scan -> mu, istd ----------------
// one block per batch, 256 threads x 8 elements, double precision scans
__global__ __launch_bounds__(256) void scan_kernel(float* __restrict__ ws) {
    int b = blockIdx.x;
    int tid = threadIdx.x;
    int lane = tid & 63;
    int wv = tid >> 6;
    const float* S1 = ws + S1_OFF + b*TT_OUT;
    const float* SS = ws + SS_OFF + b*TT_OUT;
    float* MU = ws + MU_OFF + b*TT_OUT;
    float* ISTD = ws + ISTD_OFF + b*TT_OUT;
    __shared__ double wsum_lds[4];

    double s1loc[8], v[8];
    double tot = 0.0;
#pragma unroll
    for (int i = 0; i < 8; ++i) { s1loc[i] = (double)S1[tid*8+i]; tot += s1loc[i]; v[i] = tot; }
    // wave inclusive scan of tot
    double incl = tot;
#pragma unroll
    for (int off = 1; off < 64; off <<= 1) {
        double n = __shfl_up(incl, off);
        if (lane >= off) incl += n;
    }
    if (lane == 63) wsum_lds[wv] = incl;
    __syncthreads();
    double woff = 0.0;
    for (int w2 = 0; w2 < wv; ++w2) woff += wsum_lds[w2];
    double prefix = woff + incl - tot;   // exclusive prefix for this thread

    double muloc[8], sqv[8], v2[8];
    double tot2 = 0.0;
#pragma unroll
    for (int i = 0; i < 8; ++i) {
        int t = tid*8 + i;
        double cs = prefix + v[i];
        double cnt = (double)(t+1) * 8192.0;
        double mu = cs / cnt;
        double sq = (double)SS[t] - 2.0*mu*s1loc[i] + 8192.0*mu*mu;
        muloc[i] = mu;
        tot2 += sq; v2[i] = tot2;
    }
    double incl2 = tot2;
#pragma unroll
    for (int off = 1; off < 64; off <<= 1) {
        double n = __shfl_up(incl2, off);
        if (lane >= off) incl2 += n;
    }
    __syncthreads();   // protect wsum_lds reuse
    if (lane == 63) wsum_lds[wv] = incl2;
    __syncthreads();
    double woff2 = 0.0;
    for (int w2 = 0; w2 < wv; ++w2) woff2 += wsum_lds[w2];
    double prefix2 = woff2 + incl2 - tot2;
#pragma unroll
    for (int i = 0; i < 8; ++i) {
        int t = tid*8 + i;
        double cnt = (double)(t+1) * 8192.0;
        double var = (prefix2 + v2[i]) / cnt;
        MU[t] = (float)muloc[i];
        ISTD[t] = rsqrtf((float)var + EPS_GN);
    }
}

// ---------------- kernel 3: fused conv + norm + relu + write ----------------
#define T_TILE 16
#define CG 16
__global__ __launch_bounds__(256) void out_kernel(const float* __restrict__ x,
        const float* __restrict__ w, const float* __restrict__ scale,
        const float* __restrict__ ws, float* __restrict__ out) {
    __shared__ float wl[CG][9];
    __shared__ float sl[CG];
    int tid = threadIdx.x;
    int b = blockIdx.z;
    int c0 = blockIdx.y * CG;
    int t0 = blockIdx.x * T_TILE;
    if (tid < CG*9) wl[tid/9][tid%9] = w[c0*9 + tid];
    if (tid < CG) sl[tid] = scale[c0 + tid];
    __syncthreads();
    int f = tid & 63;
    int trow = tid >> 6;
    const float* xb = x + (size_t)b * (X_H * X_W);
    const float* MU = ws + MU_OFF + b*TT_OUT;
    const float* ISTD = ws + ISTD_OFF + b*TT_OUT;
#pragma unroll
    for (int it = 0; it < T_TILE/4; ++it) {
        int t = t0 + it*4 + trow;
        float mu = MU[t];
        float istd = ISTD[t];
        float xv[9];
        int r0 = 2*t - 1;
#pragma unroll
        for (int kh = 0; kh < 3; ++kh) {
            int r = r0 + kh;
            bool rok = (r >= 0) && (r < X_H);
#pragma unroll
            for (int kw = 0; kw < 3; ++kw) {
                int cidx = 2*f + kw;
                xv[kh*3+kw] = (rok && cidx < X_W) ? xb[(size_t)r * X_W + cidx] : 0.f;
            }
        }
        float* ob = out + (((size_t)(b*CH + c0) * TT_OUT + t) * FF + f);
#pragma unroll
        for (int c = 0; c < CG; ++c) {
            float h = 0.f;
#pragma unroll
            for (int k = 0; k < 9; ++k) h = fmaf(wl[c][k], xv[k], h);
            float a = istd * sl[c];
            float val = fmaf(h, a, -mu * a);
            val = fmaxf(val, 0.f);
            ob[(size_t)c * (TT_OUT * FF)] = val;
        }
    }
}

extern "C" void kernel_launch(void* const* d_in, const int* in_sizes, int n_in,
                              void* d_out, int out_size, void* d_ws, size_t ws_size,
                              hipStream_t stream) {
    const float* x     = (const float*)d_in[0];
    const float* w     = (const float*)d_in[1];
    const float* scale = (const float*)d_in[2];
    float* out = (float*)d_out;
    float* ws  = (float*)d_ws;

    prep_kernel<<<1, 128, 0, stream>>>(w, ws);
    stats_kernel<<<(BATCH*TT_OUT)/4, 256, 0, stream>>>(x, ws);
    scan_kernel<<<BATCH, 256, 0, stream>>>(ws);
    out_kernel<<<dim3(TT_OUT/T_TILE, CH/CG, BATCH), 256, 0, stream>>>(x, w, scale, ws, out);
}

// Round 2
// 62.660 us; speedup vs baseline: 1.0416x; 1.0416x over previous
//
#include <hip/hip_runtime.h>

#define X_H 4096
#define X_W 128
#define BATCH 4
#define CH 128
#define TT_OUT 2048
#define FF 64
#define EPS_GN 1e-3f

typedef float f4 __attribute__((ext_vector_type(4)));
typedef float f2 __attribute__((ext_vector_type(2)));

// workspace float offsets
#define S1_OFF 0
#define SS_OFF (BATCH*TT_OUT)
#define MI_OFF (2*BATCH*TT_OUT)   // float2 per (b,t): {mu, istd}

// ---------------- kernel 1: per-(b,t) S1, SS (prep fused) ----------------
// block = 256 threads: fq = tid&15 (4 f's each), tr = tid>>4 (16 t's per block)
__global__ __launch_bounds__(256) void stats_kernel(const float* __restrict__ x,
                                                    const float* __restrict__ w,
                                                    float* __restrict__ ws) {
    __shared__ float Ml[81];
    __shared__ float Wl[9];
    int tid = threadIdx.x;
    if (tid < 81) {
        int j = tid / 9, k = tid % 9;
        float acc = 0.f;
        for (int c = 0; c < CH; ++c) acc = fmaf(w[c*9 + j], w[c*9 + k], acc);
        Ml[tid] = acc;
    } else if (tid < 90) {
        int k = tid - 81;
        float acc = 0.f;
        for (int c = 0; c < CH; ++c) acc += w[c*9 + k];
        Wl[k] = acc;
    }
    __syncthreads();

    int fq = tid & 15;
    int tr = tid >> 4;
    int gt = blockIdx.x * 16 + tr;          // b*2048 + t
    int t = gt & (TT_OUT - 1);
    int b = gt >> 11;
    const float* xb = x + (size_t)b * (X_H * X_W);

    float xr[3][9];
    int r0 = 2*t - 1;
#pragma unroll
    for (int kh = 0; kh < 3; ++kh) {
        int r = r0 + kh;
        if (r >= 0 && r < X_H) {
            const float* rp = xb + (size_t)r * X_W + 8*fq;
            f4 v0 = *(const f4*)rp;
            f4 v1 = *(const f4*)(rp + 4);
            xr[kh][0]=v0.x; xr[kh][1]=v0.y; xr[kh][2]=v0.z; xr[kh][3]=v0.w;
            xr[kh][4]=v1.x; xr[kh][5]=v1.y; xr[kh][6]=v1.z; xr[kh][7]=v1.w;
            xr[kh][8] = (fq == 15) ? 0.f : rp[8];
        } else {
#pragma unroll
            for (int k = 0; k < 9; ++k) xr[kh][k] = 0.f;
        }
    }

    float s1 = 0.f, ss = 0.f;
#pragma unroll
    for (int jf = 0; jf < 4; ++jf) {
        float tv[9];
#pragma unroll
        for (int kh = 0; kh < 3; ++kh)
#pragma unroll
            for (int kw = 0; kw < 3; ++kw)
                tv[kh*3+kw] = xr[kh][2*jf + kw];
#pragma unroll
        for (int k = 0; k < 9; ++k) s1 = fmaf(Wl[k], tv[k], s1);
#pragma unroll
        for (int j = 0; j < 9; ++j) {
            float tj = 0.f;
#pragma unroll
            for (int k = 0; k < 9; ++k) tj = fmaf(Ml[j*9+k], tv[k], tj);
            ss = fmaf(tv[j], tj, ss);
        }
    }
#pragma unroll
    for (int off = 1; off < 16; off <<= 1) {
        s1 += __shfl_xor(s1, off);
        ss += __shfl_xor(ss, off);
    }
    if (fq == 0) {
        ws[S1_OFF + gt] = s1;
        ws[SS_OFF + gt] = ss;
    }
}

// ---------------- kernel 2: cumulative scan -> {mu, istd} ----------------
__global__ __launch_bounds__(256) void scan_kernel(float* __restrict__ ws) {
    int b = blockIdx.x;
    int tid = threadIdx.x;
    int lane = tid & 63;
    int wv = tid >> 6;
    const float* S1 = ws + S1_OFF + b*TT_OUT;
    const float* SS = ws + SS_OFF + b*TT_OUT;
    f2* MI = (f2*)(ws + MI_OFF) + b*TT_OUT;
    __shared__ double wsum_lds[4];

    double s1loc[8], v[8];
    double tot = 0.0;
#pragma unroll
    for (int i = 0; i < 8; ++i) { s1loc[i] = (double)S1[tid*8+i]; tot += s1loc[i]; v[i] = tot; }
    double incl = tot;
#pragma unroll
    for (int off = 1; off < 64; off <<= 1) {
        double n = __shfl_up(incl, off);
        if (lane >= off) incl += n;
    }
    if (lane == 63) wsum_lds[wv] = incl;
    __syncthreads();
    double woff = 0.0;
    for (int w2 = 0; w2 < wv; ++w2) woff += wsum_lds[w2];
    double prefix = woff + incl - tot;

    double muloc[8], v2[8];
    double tot2 = 0.0;
#pragma unroll
    for (int i = 0; i < 8; ++i) {
        int t = tid*8 + i;
        double cs = prefix + v[i];
        double cnt = (double)(t+1) * 8192.0;
        double mu = cs / cnt;
        double sq = (double)SS[t] - 2.0*mu*s1loc[i] + 8192.0*mu*mu;
        muloc[i] = mu;
        tot2 += sq; v2[i] = tot2;
    }
    double incl2 = tot2;
#pragma unroll
    for (int off = 1; off < 64; off <<= 1) {
        double n = __shfl_up(incl2, off);
        if (lane >= off) incl2 += n;
    }
    __syncthreads();
    if (lane == 63) wsum_lds[wv] = incl2;
    __syncthreads();
    double woff2 = 0.0;
    for (int w2 = 0; w2 < wv; ++w2) woff2 += wsum_lds[w2];
    double prefix2 = woff2 + incl2 - tot2;
#pragma unroll
    for (int i = 0; i < 8; ++i) {
        int t = tid*8 + i;
        double cnt = (double)(t+1) * 8192.0;
        double var = (prefix2 + v2[i]) / cnt;
        f2 mi;
        mi.x = (float)muloc[i];
        mi.y = rsqrtf((float)var + EPS_GN);
        MI[t] = mi;
    }
}

// ---------------- kernel 3: fused conv + norm + relu, float4 nt stores ----
#define T_TILE 16
#define CG 16
__global__ __launch_bounds__(256) void out_kernel(const float* __restrict__ x,
        const float* __restrict__ w, const float* __restrict__ scale,
        const float* __restrict__ ws, float* __restrict__ out) {
    __shared__ float wl[CG][9];
    __shared__ float sl[CG];
    int tid = threadIdx.x;
    int b = blockIdx.z;
    int c0 = blockIdx.y * CG;
    int t0 = blockIdx.x * T_TILE;
    if (tid < CG*9) wl[tid/9][tid%9] = w[c0*9 + tid];
    if (tid < CG) sl[tid] = scale[c0 + tid];
    __syncthreads();

    int fq = tid & 15;          // 4 f's: f = 4*fq .. 4*fq+3
    int tr = tid >> 4;          // 0..15
    int t = t0 + tr;
    const float* xb = x + (size_t)b * (X_H * X_W);
    f2 mi = ((const f2*)(ws + MI_OFF))[b*TT_OUT + t];
    float mu = mi.x, istd = mi.y;

    float xr[3][9];
    int r0 = 2*t - 1;
#pragma unroll
    for (int kh = 0; kh < 3; ++kh) {
        int r = r0 + kh;
        if (r >= 0 && r < X_H) {
            const float* rp = xb + (size_t)r * X_W + 8*fq;
            f4 v0 = *(const f4*)rp;
            f4 v1 = *(const f4*)(rp + 4);
            xr[kh][0]=v0.x; xr[kh][1]=v0.y; xr[kh][2]=v0.z; xr[kh][3]=v0.w;
            xr[kh][4]=v1.x; xr[kh][5]=v1.y; xr[kh][6]=v1.z; xr[kh][7]=v1.w;
            xr[kh][8] = (fq == 15) ? 0.f : rp[8];
        } else {
#pragma unroll
            for (int k = 0; k < 9; ++k) xr[kh][k] = 0.f;
        }
    }

    float* ob = out + (((size_t)(b*CH + c0) * TT_OUT + t) * FF + 4*fq);
#pragma unroll
    for (int c = 0; c < CG; ++c) {
        float a  = istd * sl[c];
        float nb = -mu * a;
        f4 v;
#pragma unroll
        for (int jf = 0; jf < 4; ++jf) {
            float h = 0.f;
#pragma unroll
            for (int kh = 0; kh < 3; ++kh)
#pragma unroll
                for (int kw = 0; kw < 3; ++kw)
                    h = fmaf(wl[c][kh*3+kw], xr[kh][2*jf + kw], h);
            float val = fmaxf(fmaf(h, a, nb), 0.f);
            v[jf] = val;
        }
        __builtin_nontemporal_store(v, (f4*)(ob + (size_t)c * (TT_OUT * FF)));
    }
}

extern "C" void kernel_launch(void* const* d_in, const int* in_sizes, int n_in,
                              void* d_out, int out_size, void* d_ws, size_t ws_size,
                              hipStream_t stream) {
    const float* x     = (const float*)d_in[0];
    const float* w     = (const float*)d_in[1];
    const float* scale = (const float*)d_in[2];
    float* out = (float*)d_out;
    float* ws  = (float*)d_ws;

    stats_kernel<<<(BATCH*TT_OUT)/16, 256, 0, stream>>>(x, w, ws);
    scan_kernel<<<BATCH, 256, 0, stream>>>(ws);
    out_kernel<<<dim3(TT_OUT/T_TILE, CH/CG, BATCH), 256, 0, stream>>>(x, w, scale, ws, out);
}